// Round 14
// baseline (3666.571 us; speedup 1.0000x reference)
//
// BiLSTM tagger — MI355X. Round 14: revert R13 (direct-ring loads exposed MALL
// latency on the MFMA path, +150us/scan); back to R12's cooperative LDS stage.
// New: per-kh0-wave flags. Barrier-3 existed only so tid0 could post one
// block flag after ALL waves drained; barrier-2 already orders every LDS
// hazard (proof in theory). Now each kh0 wave posts its own padded flag right
// after its own vmcnt(0); consumers poll 128 flags/dir (2/lane). One less
// barrier per step; flag no longer gated on the block's slowest wave.
#include <hip/hip_runtime.h>

typedef unsigned short u16;
typedef unsigned long long ull;
typedef short short8 __attribute__((ext_vector_type(8)));
typedef float float4_ __attribute__((ext_vector_type(4)));
typedef short8 short8a __attribute__((may_alias));
typedef float4_ float4a __attribute__((may_alias));
typedef ull ulla __attribute__((may_alias));

#define MFMA16(a, b, c) __builtin_amdgcn_mfma_f32_16x16x32_bf16((a), (b), (c), 0, 0, 0)

static __device__ __forceinline__ float b2f(u16 v) { return __uint_as_float(((unsigned)v) << 16); }
static __device__ __forceinline__ u16 f2b(float f) {
  unsigned x = __float_as_uint(f);
  return (u16)((x + 0x7fffu + ((x >> 16) & 1u)) >> 16);
}
static __device__ __forceinline__ float ldv(const void* p, long long i, int isbf) {
  return isbf ? b2f(((const u16*)p)[i]) : ((const float*)p)[i];
}
static __device__ __forceinline__ float sigm(float x) { return 1.f / (1.f + __expf(-x)); }
static __device__ __forceinline__ float tanh_(float x) { return 1.f - 2.f / (__expf(2.f * x) + 1.f); }
static __device__ __forceinline__ float4_ splat4(float v) { float4_ r; r[0]=v; r[1]=v; r[2]=v; r[3]=v; return r; }

// async global->LDS, 16B per lane (wave-uniform LDS base + lane*16)
static __device__ __forceinline__ void gload16(const u16* g, u16* l) {
  __builtin_amdgcn_global_load_lds((const __attribute__((address_space(1))) unsigned int*)g,
                                   (__attribute__((address_space(3))) unsigned int*)l, 16, 0, 0);
}

// ---------------- dtype detection (f32 vs bf16 input buffers) ----------------
__global__ __launch_bounds__(256) void k_detect(const unsigned* __restrict__ wtag, int* __restrict__ flag) {
  __shared__ int cs;
  if (threadIdx.x == 0) cs = 0;
  __syncthreads();
  int hits = 0;
  for (int i = threadIdx.x; i < 1024; i += 256) {
    unsigned b = (wtag[i] >> 8) & 0x7fu;
    hits += (b >= 0x36u && b <= 0x3fu) ? 1 : 0;
  }
  atomicAdd(&cs, hits);
  __syncthreads();
  if (threadIdx.x == 0) *flag = (cs > 512) ? 1 : 0;
}

// ---------------- weight conversion to bf16 workspace (x8 vectorized) ----------------
struct WSegs { const void* src[15]; int dst[15]; int n[15]; };
__global__ __launch_bounds__(256) void k_convw(WSegs s, u16* __restrict__ wt, const int* __restrict__ flagp) {
  const int isbf = *flagp;
  const long long total8 = 9830400 / 8;
  for (long long i8 = (long long)blockIdx.x * 256 + threadIdx.x; i8 < total8; i8 += (long long)gridDim.x * 256) {
    const long long i = i8 * 8;
    int k = 0;
#pragma unroll
    for (int j = 1; j < 15; ++j) if (i >= (long long)s.dst[j]) k = j;
    const long long loc = i - s.dst[k];
    short8 out;
    if (!s.src[k]) {
      for (int j = 0; j < 8; ++j) out[j] = 0;
    } else if (isbf) {
      out = *(const short8a*)((const u16*)s.src[k] + loc);
    } else {
      const float* fp = (const float*)s.src[k] + loc;
      const float4_ f0 = *(const float4a*)fp;
      const float4_ f1 = *(const float4a*)(fp + 4);
#pragma unroll
      for (int j = 0; j < 4; ++j) { out[j] = (short)f2b(f0[j]); out[j + 4] = (short)f2b(f1[j]); }
    }
    *(short8a*)(wt + i) = out;
  }
}

struct BSegs { const void* a[8]; const void* b[8]; int dst[8]; int n[8]; int np[8]; };
__global__ __launch_bounds__(256) void k_convb(BSegs s, float* __restrict__ bias, const int* __restrict__ flagp) {
  const int isbf = *flagp;
  for (int i = blockIdx.x * 256 + threadIdx.x; i < 9536; i += gridDim.x * 256) {
    int k = 0;
#pragma unroll
    for (int j = 1; j < 8; ++j) if (i >= s.dst[j]) k = j;
    const int loc = i - s.dst[k];
    float v = 0.f;
    if (loc < s.n[k]) {
      v = ldv(s.a[k], loc, isbf);
      if (s.b[k]) v += ldv(s.b[k], loc, isbf);
    }
    bias[i] = v;
  }
}

// ---------------- word embedding gather into cat[:,0:256] ----------------
__global__ __launch_bounds__(128) void k_wordgather(const int* __restrict__ sent, const void* __restrict__ wemb,
                                                    u16* __restrict__ cat, const int* __restrict__ flagp) {
  const int n = blockIdx.x;
  const int idx = sent[n];
  const int isbf = *flagp;
  for (int d = threadIdx.x; d < 256; d += 128)
    cat[(long long)n * 512 + d] = f2b(ldv(wemb, (long long)idx * 256 + d, isbf));
}

// ---------------- char biLSTM: 64 seqs/block, 16 steps, D=64 H=128 ----------------
__global__ __launch_bounds__(256) void k_char(const int* __restrict__ cs, const void* __restrict__ wchar,
                                              const u16* __restrict__ wihF, const u16* __restrict__ whhF,
                                              const u16* __restrict__ wihB, const u16* __restrict__ whhB,
                                              const float* __restrict__ biasF, const float* __restrict__ biasB,
                                              u16* __restrict__ cat, const int* __restrict__ flagp) {
  const int dir = blockIdx.y;
  const int nb = blockIdx.x;
  const u16* wih = dir ? wihB : wihF;
  const u16* whh = dir ? whhB : whhF;
  const float* bias = dir ? biasB : biasF;
  const int isbf = *flagp;
  __shared__ __align__(16) u16 xs[64][72];
  __shared__ __align__(16) u16 hs[64][136];
  const int tid = threadIdx.x, wv = tid >> 6, lane = tid & 63;
  for (int i = tid; i < 64 * 136; i += 256) ((u16*)hs)[i] = 0;
  float c[2][4][4];
#pragma unroll
  for (int a1 = 0; a1 < 2; ++a1)
#pragma unroll
    for (int a2 = 0; a2 < 4; ++a2)
#pragma unroll
      for (int a3 = 0; a3 < 4; ++a3) c[a1][a2][a3] = 0.f;

  for (int tt = 0; tt < 16; ++tt) {
    const int t = dir ? (15 - tt) : tt;
    {
      const int sid = tid >> 2, part = tid & 3;
      const int n = nb * 64 + sid;
      const int idx = cs[n * 16 + t];
#pragma unroll
      for (int q = 0; q < 16; ++q) {
        const int d2 = part * 16 + q;
        float v = 0.f;
        if (idx != 0) v = ldv(wchar, (long long)idx * 64 + d2, isbf);
        xs[sid][d2] = f2b(v);
      }
    }
    __syncthreads();
    float4_ acc[2][4][4];
#pragma unroll
    for (int ut = 0; ut < 2; ++ut)
#pragma unroll
      for (int g = 0; g < 4; ++g) {
        const float bv = bias[g * 128 + (wv + 4 * ut) * 16 + (lane & 15)];
#pragma unroll
        for (int rt = 0; rt < 4; ++rt) acc[ut][g][rt] = splat4(bv);
      }
#pragma unroll
    for (int kc = 0; kc < 6; ++kc) {
      short8 a[4];
      if (kc < 2) {
#pragma unroll
        for (int rt = 0; rt < 4; ++rt)
          a[rt] = *(const short8a*)&xs[rt * 16 + (lane & 15)][kc * 32 + (lane >> 4) * 8];
      } else {
#pragma unroll
        for (int rt = 0; rt < 4; ++rt)
          a[rt] = *(const short8a*)&hs[rt * 16 + (lane & 15)][(kc - 2) * 32 + (lane >> 4) * 8];
      }
#pragma unroll
      for (int ut = 0; ut < 2; ++ut)
#pragma unroll
        for (int g = 0; g < 4; ++g) {
          const int col = g * 128 + (wv + 4 * ut) * 16 + (lane & 15);
          short8 bfr;
          if (kc < 2) bfr = *(const short8a*)(wih + col * 64 + kc * 32 + (lane >> 4) * 8);
          else        bfr = *(const short8a*)(whh + col * 128 + (kc - 2) * 32 + (lane >> 4) * 8);
#pragma unroll
          for (int rt = 0; rt < 4; ++rt) acc[ut][g][rt] = MFMA16(a[rt], bfr, acc[ut][g][rt]);
        }
    }
    __syncthreads();
#pragma unroll
    for (int ut = 0; ut < 2; ++ut)
#pragma unroll
      for (int rt = 0; rt < 4; ++rt)
#pragma unroll
        for (int r = 0; r < 4; ++r) {
          const float iv = acc[ut][0][rt][r];
          const float fv = acc[ut][1][rt][r];
          const float gv = acc[ut][2][rt][r];
          const float ov = acc[ut][3][rt][r];
          float& cc = c[ut][rt][r];
          cc = sigm(fv) * cc + sigm(iv) * tanh_(gv);
          const float h = sigm(ov) * tanh_(cc);
          const int seq = rt * 16 + (lane >> 4) * 4 + r;
          const int u = (wv + 4 * ut) * 16 + (lane & 15);
          const u16 hv = f2b(h);
          hs[seq][u] = hv;
          if (tt == 15) cat[(long long)(nb * 64 + seq) * 512 + 256 + dir * 128 + u] = hv;
        }
  }
}

// ---------------- m97-pattern MFMA GEMM: 128x128 tile, gload_lds staging ----------------
template <int PERM, int OUTM>
__global__ __launch_bounds__(256) void k_gemm2(const u16* __restrict__ A, const u16* __restrict__ Wt,
                                               const float* __restrict__ bias, void* __restrict__ Cout,
                                               const int N, const int K, const int ldc,
                                               const int* __restrict__ flagp) {
  __shared__ __align__(16) u16 As[128 * 64];
  __shared__ __align__(16) u16 Bs[128 * 64];
  const int bm = blockIdx.x, bn = blockIdx.y;
  const int tid = threadIdx.x, wv = tid >> 6, lane = tid & 63;
  const int l15 = lane & 15, q = lane >> 4;
  const int wr = wv >> 1, wc = wv & 1;
  const int srow = tid >> 3, sseg = tid & 7;
  float4_ acc[4][4];
#pragma unroll
  for (int mt = 0; mt < 4; ++mt)
#pragma unroll
    for (int nt = 0; nt < 4; ++nt) acc[mt][nt] = splat4(0.f);
  const int nk = K >> 6;
  for (int kc = 0; kc < nk; ++kc) {
    __syncthreads();
#pragma unroll
    for (int j = 0; j < 4; ++j) {
      const int row = srow + j * 32;
      gload16(A + (long long)(bm * 128 + row) * K + kc * 64 + sseg * 8, &As[row * 64 + sseg * 8]);
      gload16(Wt + (long long)(bn * 128 + row) * K + kc * 64 + sseg * 8, &Bs[row * 64 + sseg * 8]);
    }
    asm volatile("s_waitcnt vmcnt(0)" ::: "memory");
    __syncthreads();
#pragma unroll
    for (int kk = 0; kk < 2; ++kk) {
      short8 af[4], bf[4];
#pragma unroll
      for (int mt = 0; mt < 4; ++mt)
        af[mt] = *(const short8a*)&As[(wr * 64 + mt * 16 + l15) * 64 + kk * 32 + q * 8];
#pragma unroll
      for (int nt = 0; nt < 4; ++nt)
        bf[nt] = *(const short8a*)&Bs[(wc * 64 + nt * 16 + l15) * 64 + kk * 32 + q * 8];
#pragma unroll
      for (int mt = 0; mt < 4; ++mt)
#pragma unroll
        for (int nt = 0; nt < 4; ++nt)
          acc[mt][nt] = MFMA16(af[mt], bf[nt], acc[mt][nt]);
    }
  }
  const int isbf = (OUTM == 1) ? *flagp : 0;
#pragma unroll
  for (int mt = 0; mt < 4; ++mt)
#pragma unroll
    for (int nt = 0; nt < 4; ++nt)
#pragma unroll
      for (int r = 0; r < 4; ++r) {
        const int row = bm * 128 + wr * 64 + mt * 16 + q * 4 + r;
        const int col = bn * 128 + wc * 64 + nt * 16 + l15;
        if (col < N) {
          const float v = acc[mt][nt][r] + bias[col];
          long long orow;
          if (PERM == 0) orow = row;
          else orow = (long long)(row & 255) * 64 + (row >> 8);
          if (OUTM == 0) ((u16*)Cout)[orow * ldc + col] = f2b(v);
          else if (isbf) ((u16*)Cout)[orow * ldc + col] = f2b(v);
          else ((float*)Cout)[orow * ldc + col] = v;
        }
      }
}

// ---------------- small GEMM (tag projection only) ----------------
template <int TM, int TN, int PERM, int OUTM>
__global__ __launch_bounds__(256) void k_gemm(const u16* __restrict__ A, const u16* __restrict__ Wt,
                                              const float* __restrict__ bias, void* __restrict__ Cout,
                                              const int N, const int K, const int ldc,
                                              const int* __restrict__ flagp) {
  constexpr int RT = TM / 16;
  constexpr int CPW = TN / 64;
  const int bm = blockIdx.x, bn = blockIdx.y;
  const int tid = threadIdx.x, wv = tid >> 6, lane = tid & 63;
  __shared__ __align__(16) u16 As[TM][72];
  float4_ acc[CPW][RT];
#pragma unroll
  for (int ci = 0; ci < CPW; ++ci)
#pragma unroll
    for (int rt = 0; rt < RT; ++rt) acc[ci][rt] = splat4(0.f);
  const int nk = K >> 6;
  for (int kc = 0; kc < nk; ++kc) {
    __syncthreads();
    for (int idx = tid; idx < TM * 4; idx += 256) {
      const int r = idx >> 2, sg = idx & 3;
      const u16* src = A + (long long)(bm * TM + r) * K + kc * 64 + sg * 16;
      *(short8a*)&As[r][sg * 16] = *(const short8a*)src;
      *(short8a*)&As[r][sg * 16 + 8] = *(const short8a*)(src + 8);
    }
    __syncthreads();
#pragma unroll
    for (int kk = 0; kk < 2; ++kk) {
      short8 af[RT];
#pragma unroll
      for (int rt = 0; rt < RT; ++rt)
        af[rt] = *(const short8a*)&As[rt * 16 + (lane & 15)][kk * 32 + (lane >> 4) * 8];
#pragma unroll
      for (int ci = 0; ci < CPW; ++ci) {
        const int ct = wv + ci * 4;
        const short8 bf = *(const short8a*)(Wt + (long long)(bn * TN + ct * 16 + (lane & 15)) * K +
                                            kc * 64 + kk * 32 + (lane >> 4) * 8);
#pragma unroll
        for (int rt = 0; rt < RT; ++rt) acc[ci][rt] = MFMA16(af[rt], bf, acc[ci][rt]);
      }
    }
  }
  const int isbf = (OUTM == 1) ? *flagp : 0;
#pragma unroll
  for (int ci = 0; ci < CPW; ++ci)
#pragma unroll
    for (int rt = 0; rt < RT; ++rt)
#pragma unroll
      for (int r = 0; r < 4; ++r) {
        const int row = bm * TM + rt * 16 + (lane >> 4) * 4 + r;
        const int col = bn * TN + (wv + ci * 4) * 16 + (lane & 15);
        if (col < N) {
          const float v = acc[ci][rt][r] + bias[col];
          long long orow;
          if (PERM == 0) orow = row;
          else if (PERM == 1) orow = (long long)(row & 255) * 64 + (row >> 8);
          else orow = (long long)(row & 63) * 256 + (row >> 6);
          if (OUTM == 0) ((u16*)Cout)[orow * ldc + col] = f2b(v);
          else if (isbf) ((u16*)Cout)[orow * ldc + col] = f2b(v);
          else ((float*)Cout)[orow * ldc + col] = v;
        }
      }
}

// ---------------- persistent LSTM scan (one layer, both dirs) ----------------
// grid (32, 2=dir), 512 threads (8 waves = (kh, bt)). R12 stage/compute body;
// sync: per-kh0-wave flags (128/dir, 128B stride) posted after each wave's own
// vmcnt(0); 2 barriers/step (barrier-2 proves all LDS hazards ordered).
__global__ __launch_bounds__(512, 1) void k_scan(const u16* __restrict__ pre0, const u16* __restrict__ pre1,
                                                 const u16* __restrict__ whh0, const u16* __restrict__ whh1,
                                                 u16* __restrict__ o_out, const u16* __restrict__ zbuf,
                                                 int* __restrict__ flags) {
  const int dir = blockIdx.y, blk = blockIdx.x;
  const u16* __restrict__ pre = dir ? pre1 : pre0;
  const u16* __restrict__ whh = dir ? whh1 : whh0;
  int* myflags = flags + dir * 4096;  // 128 flags, 32-int (128B) stride
  const int u0 = blk * 16;
  __shared__ __align__(16) u16 hstage[64 * 512];   // 64KB, XOR-swizzled rows
  __shared__ __align__(16) float xch[4][64][16];   // 16KB gate partials (kh=1)
  const int tid = threadIdx.x, lane = tid & 63;
  const int wv = tid >> 6;
  const int l15 = lane & 15, q = lane >> 4;
  const int kh = wv >> 2, bt = wv & 3;
  const int b = bt * 16 + l15;        // batch this thread's fragment covers

  // weights: 4 gates x 8 kc fragments (rows g*512+u0+l15, k = kh*256+kc*32+q*8)
  float4_ swf[4][8];
#pragma unroll
  for (int g = 0; g < 4; ++g)
#pragma unroll
    for (int kc = 0; kc < 8; ++kc)
      swf[g][kc] = *(const float4a*)(whh + (long long)(g * 512 + u0 + l15) * 512 +
                                     kh * 256 + kc * 32 + q * 8);

  float c4[4];
#pragma unroll
  for (int j = 0; j < 4; ++j) c4[j] = 0.f;

  ull pr[4], prn[4];
  if (kh == 0) {
    const int t0 = dir ? 255 : 0;
    const u16* pb = pre + (long long)(t0 * 64 + b) * 2048 + u0 + q * 4;
#pragma unroll
    for (int g = 0; g < 4; ++g) pr[g] = *(const ulla*)(pb + g * 512);
  }

  for (int tt = 0; tt < 256; ++tt) {
    const int t = dir ? (255 - tt) : tt;

    // ---- stage h_{t-1}: coalesced (per-wave 1KB contiguous per b128) ----
    {
      const u16* base;
      if (tt == 0) {
        base = zbuf + dir * 512;
      } else {
        const int tp = dir ? (t + 1) : (t - 1);
        base = o_out + (long long)tp * 65536 + dir * 512;
      }
      const int off = lane * 8;
#pragma unroll
      for (int it = 0; it < 8; ++it) {
        const int row = wv + it * 8;
        const float4_ v = *(const float4a*)(base + (long long)row * 1024 + off);
        *(float4a*)((char*)hstage + row * 1024 + ((off * 2) ^ ((row & 7) << 4))) = v;
      }
    }
    __syncthreads();  // barrier 1: hstage staged

    // ---- MFMA: 4 gates, one A-read per kc (reused 4x) ----
    float4_ acc[4];
#pragma unroll
    for (int g = 0; g < 4; ++g) acc[g] = splat4(0.f);
    const char* hsb = (const char*)hstage;
#pragma unroll
    for (int kc = 0; kc < 8; ++kc) {
      const int row = b;
      const short8 A = *(const short8a*)(hsb + row * 1024 +
                        ((kh * 512 + kc * 64 + q * 16) ^ ((row & 7) << 4)));
      acc[0] = MFMA16(__builtin_bit_cast(short8, swf[0][kc]), A, acc[0]);
      acc[1] = MFMA16(__builtin_bit_cast(short8, swf[1][kc]), A, acc[1]);
      acc[2] = MFMA16(__builtin_bit_cast(short8, swf[2][kc]), A, acc[2]);
      acc[3] = MFMA16(__builtin_bit_cast(short8, swf[3][kc]), A, acc[3]);
    }

    // ---- exchange: kh=1 writes partials ----
    if (kh == 1) {
#pragma unroll
      for (int g = 0; g < 4; ++g)
        *(float4a*)&xch[g][b][(q ^ (l15 & 3)) * 4] = acc[g];
    }
    __syncthreads();  // barrier 2: xch ready; all hstage/xch reads of step t done

    if (kh == 0) {
#pragma unroll
      for (int g = 0; g < 4; ++g)
        acc[g] += *(const float4a*)&xch[g][b][(q ^ (l15 & 3)) * 4];
      ull hv = 0;
#pragma unroll
      for (int j = 0; j < 4; ++j) {
        const float iv = acc[0][j] + b2f((u16)(pr[0] >> (16 * j)));
        const float fv = acc[1][j] + b2f((u16)(pr[1] >> (16 * j)));
        const float gg = acc[2][j] + b2f((u16)(pr[2] >> (16 * j)));
        const float ov = acc[3][j] + b2f((u16)(pr[3] >> (16 * j)));
        c4[j] = sigm(fv) * c4[j] + sigm(iv) * tanh_(gg);
        const float h = sigm(ov) * tanh_(c4[j]);
        hv |= (ull)f2b(h) << (16 * j);
      }
      // write-through publish into the ring (= o_out), then own-wave drain+flag
      __hip_atomic_store((ull*)(o_out + (long long)(t * 64 + b) * 1024 + dir * 512 + u0 + q * 4), hv,
                         __ATOMIC_RELAXED, __HIP_MEMORY_SCOPE_AGENT);
      asm volatile("s_waitcnt vmcnt(0)" ::: "memory");  // this wave's h at MALL
      if (lane == 0)
        __hip_atomic_store(&myflags[(blk * 4 + bt) * 32], tt + 1,
                           __ATOMIC_RELAXED, __HIP_MEMORY_SCOPE_AGENT);
      // next-step pre prefetch (in flight during the poll)
      const int ttn = (tt < 255) ? tt + 1 : tt;
      const int tn = dir ? (255 - ttn) : ttn;
      const u16* pb = pre + (long long)(tn * 64 + b) * 2048 + u0 + q * 4;
#pragma unroll
      for (int g = 0; g < 4; ++g) prn[g] = *(const ulla*)(pb + g * 512);
    }
    if (tt != 255) {
      // poll all 128 kh0-wave flags (2 per lane)
      const int* fp1 = myflags + lane * 32;
      const int* fp2 = myflags + (lane + 64) * 32;
      int v1 = __hip_atomic_load(fp1, __ATOMIC_RELAXED, __HIP_MEMORY_SCOPE_AGENT);
      int v2 = __hip_atomic_load(fp2, __ATOMIC_RELAXED, __HIP_MEMORY_SCOPE_AGENT);
      while (__all(v1 >= tt + 1 && v2 >= tt + 1) == 0) {
        __builtin_amdgcn_s_sleep(1);
        v1 = __hip_atomic_load(fp1, __ATOMIC_RELAXED, __HIP_MEMORY_SCOPE_AGENT);
        v2 = __hip_atomic_load(fp2, __ATOMIC_RELAXED, __HIP_MEMORY_SCOPE_AGENT);
      }
      asm volatile("" ::: "memory");  // stage loads may not hoist above poll
    }
    if (kh == 0) {
#pragma unroll
      for (int g = 0; g < 4; ++g) pr[g] = prn[g];
    }
#pragma unroll
    for (int g = 0; g < 4; ++g)
#pragma unroll
      for (int kc = 0; kc < 8; ++kc) asm volatile("" : "+v"(swf[g][kc]));
  }
}

// ---------------- launcher ----------------
static constexpr long long OFF_WT = 0;
static constexpr long long OFF_BIAS = 19660800;
static constexpr long long OFF_CAT = 19698944;
static constexpr long long OFF_EMB = 36476160;
static constexpr long long OFF_PRE = 44864768;
static constexpr long long OFF_O1 = 179082496;
static constexpr long long OFF_O2 = 212636928;
static constexpr long long OFF_SYNC = 246191360;
// layout: cnt1 (32KB) | cnt2 (32KB) | zbuf (128KB)
static constexpr long long SYNC_BYTES = 65536 + 131072;
static constexpr long long OFF_FLAG = OFF_SYNC + SYNC_BYTES;

extern "C" void kernel_launch(void* const* d_in, const int* in_sizes, int n_in,
                              void* d_out, int out_size, void* d_ws, size_t ws_size,
                              hipStream_t stream) {
  char* ws = (char*)d_ws;
  u16* wt = (u16*)(ws + OFF_WT);
  float* biasp = (float*)(ws + OFF_BIAS);
  u16* cat = (u16*)(ws + OFF_CAT);
  u16* emb = (u16*)(ws + OFF_EMB);
  u16* pre0 = (u16*)(ws + OFF_PRE);
  u16* pre1 = pre0 + (long long)16384 * 2048;
  u16* o1 = (u16*)(ws + OFF_O1);
  u16* o2 = (u16*)(ws + OFF_O2);
  int* cnt1 = (int*)(ws + OFF_SYNC);          // 2 dirs x 128 flags x 32-int stride
  int* cnt2 = cnt1 + 8192;
  u16* zbuf = (u16*)(ws + OFF_SYNC + 65536);  // 128KB zero slot
  int* flag = (int*)(ws + OFF_FLAG);

  hipMemsetAsync(ws + OFF_SYNC, 0, SYNC_BYTES, stream);
  k_detect<<<1, 256, 0, stream>>>((const unsigned*)d_in[30], flag);

  WSegs wsg;
  const int widx[14] = {4, 5, 8, 9, 12, 13, 16, 17, 20, 21, 24, 25, 28, 30};
  const int wdst[15] = {0, 32768, 98304, 131072, 196608, 720896, 1769472, 2293760,
                        3342336, 5439488, 6488064, 8585216, 9633792, 9764864, 9816064};
  const int wn[15] = {32768, 65536, 32768, 65536, 524288, 1048576, 524288, 1048576,
                      2097152, 1048576, 2097152, 1048576, 131072, 51200, 14336};
  for (int j = 0; j < 14; ++j) { wsg.src[j] = d_in[widx[j]]; wsg.dst[j] = wdst[j]; wsg.n[j] = wn[j]; }
  wsg.src[14] = nullptr; wsg.dst[14] = wdst[14]; wsg.n[14] = wn[14];
  k_convw<<<1200, 256, 0, stream>>>(wsg, wt, flag);

  BSegs bsg;
  const int ba[8] = {6, 10, 14, 18, 22, 26, 29, 31};
  const int bb[8] = {7, 11, 15, 19, 23, 27, -1, -1};
  const int bdst[8] = {0, 512, 1024, 3072, 5120, 7168, 9216, 9472};
  const int bn_[8] = {512, 512, 2048, 2048, 2048, 2048, 256, 50};
  const int bnp[8] = {512, 512, 2048, 2048, 2048, 2048, 256, 64};
  for (int j = 0; j < 8; ++j) {
    bsg.a[j] = d_in[ba[j]];
    bsg.b[j] = (bb[j] >= 0) ? d_in[bb[j]] : nullptr;
    bsg.dst[j] = bdst[j]; bsg.n[j] = bn_[j]; bsg.np[j] = bnp[j];
  }
  k_convb<<<40, 256, 0, stream>>>(bsg, biasp, flag);

  k_wordgather<<<16384, 128, 0, stream>>>((const int*)d_in[0], d_in[2], cat, flag);
  k_char<<<dim3(256, 2), 256, 0, stream>>>((const int*)d_in[1], d_in[3],
                                           wt + 0, wt + 32768, wt + 98304, wt + 131072,
                                           biasp + 0, biasp + 512, cat, flag);
  k_gemm2<1, 0><<<dim3(128, 2), 256, 0, stream>>>(cat, wt + 9633792, biasp + 9216, emb, 256, 512, 256, flag);
  k_gemm2<0, 0><<<dim3(128, 16), 256, 0, stream>>>(emb, wt + 196608, biasp + 1024, pre0, 2048, 256, 2048, flag);
  k_gemm2<0, 0><<<dim3(128, 16), 256, 0, stream>>>(emb, wt + 1769472, biasp + 3072, pre1, 2048, 256, 2048, flag);
  k_scan<<<dim3(32, 2), 512, 0, stream>>>(pre0, pre1, wt + 720896, wt + 2293760, o1, zbuf, cnt1);
  k_gemm2<0, 0><<<dim3(128, 16), 256, 0, stream>>>(o1, wt + 3342336, biasp + 5120, pre0, 2048, 1024, 2048, flag);
  k_gemm2<0, 0><<<dim3(128, 16), 256, 0, stream>>>(o1, wt + 6488064, biasp + 7168, pre1, 2048, 1024, 2048, flag);
  k_scan<<<dim3(32, 2), 512, 0, stream>>>(pre0, pre1, wt + 5439488, wt + 8585216, o2, zbuf, cnt2);
  k_gemm<64, 64, 2, 1><<<dim3(256, 1), 256, 0, stream>>>(o2, wt + 9764864, biasp + 9472, d_out, 50, 1024, 50, flag);
}

// Round 15
// 2773.425 us; speedup vs baseline: 1.3220x; 1.3220x over previous
//
// BiLSTM tagger — MI355X. Round 15: exact R12 scan revert (R14's per-wave
// flags quadrupled the polled-line set: FETCH +26MB, +0.4us/step; block-wide
// flag + 3 barriers was right) + two isolated non-scan fixes:
// (1) k_char embedding gather vectorized (was 16 scalar loads/thread/step);
// (2) k_wordgather vectorized (short8 / float4x2 per thread).
#include <hip/hip_runtime.h>

typedef unsigned short u16;
typedef unsigned long long ull;
typedef short short8 __attribute__((ext_vector_type(8)));
typedef float float4_ __attribute__((ext_vector_type(4)));
typedef short8 short8a __attribute__((may_alias));
typedef float4_ float4a __attribute__((may_alias));
typedef ull ulla __attribute__((may_alias));

#define MFMA16(a, b, c) __builtin_amdgcn_mfma_f32_16x16x32_bf16((a), (b), (c), 0, 0, 0)

static __device__ __forceinline__ float b2f(u16 v) { return __uint_as_float(((unsigned)v) << 16); }
static __device__ __forceinline__ u16 f2b(float f) {
  unsigned x = __float_as_uint(f);
  return (u16)((x + 0x7fffu + ((x >> 16) & 1u)) >> 16);
}
static __device__ __forceinline__ float ldv(const void* p, long long i, int isbf) {
  return isbf ? b2f(((const u16*)p)[i]) : ((const float*)p)[i];
}
static __device__ __forceinline__ float sigm(float x) { return 1.f / (1.f + __expf(-x)); }
static __device__ __forceinline__ float tanh_(float x) { return 1.f - 2.f / (__expf(2.f * x) + 1.f); }
static __device__ __forceinline__ float4_ splat4(float v) { float4_ r; r[0]=v; r[1]=v; r[2]=v; r[3]=v; return r; }

// async global->LDS, 16B per lane (wave-uniform LDS base + lane*16)
static __device__ __forceinline__ void gload16(const u16* g, u16* l) {
  __builtin_amdgcn_global_load_lds((const __attribute__((address_space(1))) unsigned int*)g,
                                   (__attribute__((address_space(3))) unsigned int*)l, 16, 0, 0);
}

// ---------------- dtype detection (f32 vs bf16 input buffers) ----------------
__global__ __launch_bounds__(256) void k_detect(const unsigned* __restrict__ wtag, int* __restrict__ flag) {
  __shared__ int cs;
  if (threadIdx.x == 0) cs = 0;
  __syncthreads();
  int hits = 0;
  for (int i = threadIdx.x; i < 1024; i += 256) {
    unsigned b = (wtag[i] >> 8) & 0x7fu;
    hits += (b >= 0x36u && b <= 0x3fu) ? 1 : 0;
  }
  atomicAdd(&cs, hits);
  __syncthreads();
  if (threadIdx.x == 0) *flag = (cs > 512) ? 1 : 0;
}

// ---------------- weight conversion to bf16 workspace (x8 vectorized) ----------------
struct WSegs { const void* src[15]; int dst[15]; int n[15]; };
__global__ __launch_bounds__(256) void k_convw(WSegs s, u16* __restrict__ wt, const int* __restrict__ flagp) {
  const int isbf = *flagp;
  const long long total8 = 9830400 / 8;
  for (long long i8 = (long long)blockIdx.x * 256 + threadIdx.x; i8 < total8; i8 += (long long)gridDim.x * 256) {
    const long long i = i8 * 8;
    int k = 0;
#pragma unroll
    for (int j = 1; j < 15; ++j) if (i >= (long long)s.dst[j]) k = j;
    const long long loc = i - s.dst[k];
    short8 out;
    if (!s.src[k]) {
      for (int j = 0; j < 8; ++j) out[j] = 0;
    } else if (isbf) {
      out = *(const short8a*)((const u16*)s.src[k] + loc);
    } else {
      const float* fp = (const float*)s.src[k] + loc;
      const float4_ f0 = *(const float4a*)fp;
      const float4_ f1 = *(const float4a*)(fp + 4);
#pragma unroll
      for (int j = 0; j < 4; ++j) { out[j] = (short)f2b(f0[j]); out[j + 4] = (short)f2b(f1[j]); }
    }
    *(short8a*)(wt + i) = out;
  }
}

struct BSegs { const void* a[8]; const void* b[8]; int dst[8]; int n[8]; int np[8]; };
__global__ __launch_bounds__(256) void k_convb(BSegs s, float* __restrict__ bias, const int* __restrict__ flagp) {
  const int isbf = *flagp;
  for (int i = blockIdx.x * 256 + threadIdx.x; i < 9536; i += gridDim.x * 256) {
    int k = 0;
#pragma unroll
    for (int j = 1; j < 8; ++j) if (i >= s.dst[j]) k = j;
    const int loc = i - s.dst[k];
    float v = 0.f;
    if (loc < s.n[k]) {
      v = ldv(s.a[k], loc, isbf);
      if (s.b[k]) v += ldv(s.b[k], loc, isbf);
    }
    bias[i] = v;
  }
}

// ---------------- word embedding gather into cat[:,0:256] (vectorized) ----------------
__global__ __launch_bounds__(256) void k_wordgather(const int* __restrict__ sent, const void* __restrict__ wemb,
                                                    u16* __restrict__ cat, const int* __restrict__ flagp) {
  const int isbf = *flagp;
  const int i = blockIdx.x * 256 + threadIdx.x;  // 524288 = 16384 rows x 32 thr
  const int n = i >> 5, j = (i & 31) * 8;
  const int idx = sent[n];
  short8 v;
  if (isbf) {
    v = *(const short8a*)((const u16*)wemb + (long long)idx * 256 + j);
  } else {
    const float* src = (const float*)wemb + (long long)idx * 256 + j;
    const float4_ f0 = *(const float4a*)src;
    const float4_ f1 = *(const float4a*)(src + 4);
#pragma unroll
    for (int jj = 0; jj < 4; ++jj) { v[jj] = (short)f2b(f0[jj]); v[jj + 4] = (short)f2b(f1[jj]); }
  }
  *(short8a*)(cat + (long long)n * 512 + j) = v;
}

// ---------------- char biLSTM: 64 seqs/block, 16 steps, D=64 H=128 ----------------
__global__ __launch_bounds__(256) void k_char(const int* __restrict__ cs, const void* __restrict__ wchar,
                                              const u16* __restrict__ wihF, const u16* __restrict__ whhF,
                                              const u16* __restrict__ wihB, const u16* __restrict__ whhB,
                                              const float* __restrict__ biasF, const float* __restrict__ biasB,
                                              u16* __restrict__ cat, const int* __restrict__ flagp) {
  const int dir = blockIdx.y;
  const int nb = blockIdx.x;
  const u16* wih = dir ? wihB : wihF;
  const u16* whh = dir ? whhB : whhF;
  const float* bias = dir ? biasB : biasF;
  const int isbf = *flagp;
  __shared__ __align__(16) u16 xs[64][72];
  __shared__ __align__(16) u16 hs[64][136];
  const int tid = threadIdx.x, wv = tid >> 6, lane = tid & 63;
  for (int i = tid; i < 64 * 136; i += 256) ((u16*)hs)[i] = 0;
  float c[2][4][4];
#pragma unroll
  for (int a1 = 0; a1 < 2; ++a1)
#pragma unroll
    for (int a2 = 0; a2 < 4; ++a2)
#pragma unroll
      for (int a3 = 0; a3 < 4; ++a3) c[a1][a2][a3] = 0.f;

  for (int tt = 0; tt < 16; ++tt) {
    const int t = dir ? (15 - tt) : tt;
    {  // vectorized gather of x_t (padding_idx==0 -> zeros)
      const int sid = tid >> 2, part = tid & 3;
      const int n = nb * 64 + sid;
      const int idx = cs[n * 16 + t];
      short8 v0, v1;
      if (idx == 0) {
#pragma unroll
        for (int j = 0; j < 8; ++j) { v0[j] = 0; v1[j] = 0; }
      } else if (isbf) {
        const u16* src = (const u16*)wchar + (long long)idx * 64 + part * 16;
        v0 = *(const short8a*)src;
        v1 = *(const short8a*)(src + 8);
      } else {
        const float* src = (const float*)wchar + (long long)idx * 64 + part * 16;
        const float4_ f0 = *(const float4a*)src;
        const float4_ f1 = *(const float4a*)(src + 4);
        const float4_ f2 = *(const float4a*)(src + 8);
        const float4_ f3 = *(const float4a*)(src + 12);
#pragma unroll
        for (int j = 0; j < 4; ++j) {
          v0[j] = (short)f2b(f0[j]); v0[j + 4] = (short)f2b(f1[j]);
          v1[j] = (short)f2b(f2[j]); v1[j + 4] = (short)f2b(f3[j]);
        }
      }
      *(short8a*)&xs[sid][part * 16] = v0;
      *(short8a*)&xs[sid][part * 16 + 8] = v1;
    }
    __syncthreads();
    float4_ acc[2][4][4];
#pragma unroll
    for (int ut = 0; ut < 2; ++ut)
#pragma unroll
      for (int g = 0; g < 4; ++g) {
        const float bv = bias[g * 128 + (wv + 4 * ut) * 16 + (lane & 15)];
#pragma unroll
        for (int rt = 0; rt < 4; ++rt) acc[ut][g][rt] = splat4(bv);
      }
#pragma unroll
    for (int kc = 0; kc < 6; ++kc) {
      short8 a[4];
      if (kc < 2) {
#pragma unroll
        for (int rt = 0; rt < 4; ++rt)
          a[rt] = *(const short8a*)&xs[rt * 16 + (lane & 15)][kc * 32 + (lane >> 4) * 8];
      } else {
#pragma unroll
        for (int rt = 0; rt < 4; ++rt)
          a[rt] = *(const short8a*)&hs[rt * 16 + (lane & 15)][(kc - 2) * 32 + (lane >> 4) * 8];
      }
#pragma unroll
      for (int ut = 0; ut < 2; ++ut)
#pragma unroll
        for (int g = 0; g < 4; ++g) {
          const int col = g * 128 + (wv + 4 * ut) * 16 + (lane & 15);
          short8 bfr;
          if (kc < 2) bfr = *(const short8a*)(wih + col * 64 + kc * 32 + (lane >> 4) * 8);
          else        bfr = *(const short8a*)(whh + col * 128 + (kc - 2) * 32 + (lane >> 4) * 8);
#pragma unroll
          for (int rt = 0; rt < 4; ++rt) acc[ut][g][rt] = MFMA16(a[rt], bfr, acc[ut][g][rt]);
        }
    }
    __syncthreads();
#pragma unroll
    for (int ut = 0; ut < 2; ++ut)
#pragma unroll
      for (int rt = 0; rt < 4; ++rt)
#pragma unroll
        for (int r = 0; r < 4; ++r) {
          const float iv = acc[ut][0][rt][r];
          const float fv = acc[ut][1][rt][r];
          const float gv = acc[ut][2][rt][r];
          const float ov = acc[ut][3][rt][r];
          float& cc = c[ut][rt][r];
          cc = sigm(fv) * cc + sigm(iv) * tanh_(gv);
          const float h = sigm(ov) * tanh_(cc);
          const int seq = rt * 16 + (lane >> 4) * 4 + r;
          const int u = (wv + 4 * ut) * 16 + (lane & 15);
          const u16 hv = f2b(h);
          hs[seq][u] = hv;
          if (tt == 15) cat[(long long)(nb * 64 + seq) * 512 + 256 + dir * 128 + u] = hv;
        }
  }
}

// ---------------- m97-pattern MFMA GEMM: 128x128 tile, gload_lds staging ----------------
template <int PERM, int OUTM>
__global__ __launch_bounds__(256) void k_gemm2(const u16* __restrict__ A, const u16* __restrict__ Wt,
                                               const float* __restrict__ bias, void* __restrict__ Cout,
                                               const int N, const int K, const int ldc,
                                               const int* __restrict__ flagp) {
  __shared__ __align__(16) u16 As[128 * 64];
  __shared__ __align__(16) u16 Bs[128 * 64];
  const int bm = blockIdx.x, bn = blockIdx.y;
  const int tid = threadIdx.x, wv = tid >> 6, lane = tid & 63;
  const int l15 = lane & 15, q = lane >> 4;
  const int wr = wv >> 1, wc = wv & 1;
  const int srow = tid >> 3, sseg = tid & 7;
  float4_ acc[4][4];
#pragma unroll
  for (int mt = 0; mt < 4; ++mt)
#pragma unroll
    for (int nt = 0; nt < 4; ++nt) acc[mt][nt] = splat4(0.f);
  const int nk = K >> 6;
  for (int kc = 0; kc < nk; ++kc) {
    __syncthreads();
#pragma unroll
    for (int j = 0; j < 4; ++j) {
      const int row = srow + j * 32;
      gload16(A + (long long)(bm * 128 + row) * K + kc * 64 + sseg * 8, &As[row * 64 + sseg * 8]);
      gload16(Wt + (long long)(bn * 128 + row) * K + kc * 64 + sseg * 8, &Bs[row * 64 + sseg * 8]);
    }
    asm volatile("s_waitcnt vmcnt(0)" ::: "memory");
    __syncthreads();
#pragma unroll
    for (int kk = 0; kk < 2; ++kk) {
      short8 af[4], bf[4];
#pragma unroll
      for (int mt = 0; mt < 4; ++mt)
        af[mt] = *(const short8a*)&As[(wr * 64 + mt * 16 + l15) * 64 + kk * 32 + q * 8];
#pragma unroll
      for (int nt = 0; nt < 4; ++nt)
        bf[nt] = *(const short8a*)&Bs[(wc * 64 + nt * 16 + l15) * 64 + kk * 32 + q * 8];
#pragma unroll
      for (int mt = 0; mt < 4; ++mt)
#pragma unroll
        for (int nt = 0; nt < 4; ++nt)
          acc[mt][nt] = MFMA16(af[mt], bf[nt], acc[mt][nt]);
    }
  }
  const int isbf = (OUTM == 1) ? *flagp : 0;
#pragma unroll
  for (int mt = 0; mt < 4; ++mt)
#pragma unroll
    for (int nt = 0; nt < 4; ++nt)
#pragma unroll
      for (int r = 0; r < 4; ++r) {
        const int row = bm * 128 + wr * 64 + mt * 16 + q * 4 + r;
        const int col = bn * 128 + wc * 64 + nt * 16 + l15;
        if (col < N) {
          const float v = acc[mt][nt][r] + bias[col];
          long long orow;
          if (PERM == 0) orow = row;
          else orow = (long long)(row & 255) * 64 + (row >> 8);
          if (OUTM == 0) ((u16*)Cout)[orow * ldc + col] = f2b(v);
          else if (isbf) ((u16*)Cout)[orow * ldc + col] = f2b(v);
          else ((float*)Cout)[orow * ldc + col] = v;
        }
      }
}

// ---------------- small GEMM (tag projection only) ----------------
template <int TM, int TN, int PERM, int OUTM>
__global__ __launch_bounds__(256) void k_gemm(const u16* __restrict__ A, const u16* __restrict__ Wt,
                                              const float* __restrict__ bias, void* __restrict__ Cout,
                                              const int N, const int K, const int ldc,
                                              const int* __restrict__ flagp) {
  constexpr int RT = TM / 16;
  constexpr int CPW = TN / 64;
  const int bm = blockIdx.x, bn = blockIdx.y;
  const int tid = threadIdx.x, wv = tid >> 6, lane = tid & 63;
  __shared__ __align__(16) u16 As[TM][72];
  float4_ acc[CPW][RT];
#pragma unroll
  for (int ci = 0; ci < CPW; ++ci)
#pragma unroll
    for (int rt = 0; rt < RT; ++rt) acc[ci][rt] = splat4(0.f);
  const int nk = K >> 6;
  for (int kc = 0; kc < nk; ++kc) {
    __syncthreads();
    for (int idx = tid; idx < TM * 4; idx += 256) {
      const int r = idx >> 2, sg = idx & 3;
      const u16* src = A + (long long)(bm * TM + r) * K + kc * 64 + sg * 16;
      *(short8a*)&As[r][sg * 16] = *(const short8a*)src;
      *(short8a*)&As[r][sg * 16 + 8] = *(const short8a*)(src + 8);
    }
    __syncthreads();
#pragma unroll
    for (int kk = 0; kk < 2; ++kk) {
      short8 af[RT];
#pragma unroll
      for (int rt = 0; rt < RT; ++rt)
        af[rt] = *(const short8a*)&As[rt * 16 + (lane & 15)][kk * 32 + (lane >> 4) * 8];
#pragma unroll
      for (int ci = 0; ci < CPW; ++ci) {
        const int ct = wv + ci * 4;
        const short8 bf = *(const short8a*)(Wt + (long long)(bn * TN + ct * 16 + (lane & 15)) * K +
                                            kc * 64 + kk * 32 + (lane >> 4) * 8);
#pragma unroll
        for (int rt = 0; rt < RT; ++rt) acc[ci][rt] = MFMA16(af[rt], bf, acc[ci][rt]);
      }
    }
  }
  const int isbf = (OUTM == 1) ? *flagp : 0;
#pragma unroll
  for (int ci = 0; ci < CPW; ++ci)
#pragma unroll
    for (int rt = 0; rt < RT; ++rt)
#pragma unroll
      for (int r = 0; r < 4; ++r) {
        const int row = bm * TM + rt * 16 + (lane >> 4) * 4 + r;
        const int col = bn * TN + (wv + ci * 4) * 16 + (lane & 15);
        if (col < N) {
          const float v = acc[ci][rt][r] + bias[col];
          long long orow;
          if (PERM == 0) orow = row;
          else if (PERM == 1) orow = (long long)(row & 255) * 64 + (row >> 8);
          else orow = (long long)(row & 63) * 256 + (row >> 6);
          if (OUTM == 0) ((u16*)Cout)[orow * ldc + col] = f2b(v);
          else if (isbf) ((u16*)Cout)[orow * ldc + col] = f2b(v);
          else ((float*)Cout)[orow * ldc + col] = v;
        }
      }
}

// ---------------- persistent LSTM scan (one layer, both dirs) — R12 exact ----------------
// grid (32, 2=dir), 512 threads (8 waves = (kh, bt)). Block flag + 3 barriers.
__global__ __launch_bounds__(512, 1) void k_scan(const u16* __restrict__ pre0, const u16* __restrict__ pre1,
                                                 const u16* __restrict__ whh0, const u16* __restrict__ whh1,
                                                 u16* __restrict__ o_out, const u16* __restrict__ zbuf,
                                                 int* __restrict__ flags) {
  const int dir = blockIdx.y, blk = blockIdx.x;
  const u16* __restrict__ pre = dir ? pre1 : pre0;
  const u16* __restrict__ whh = dir ? whh1 : whh0;
  int* myflags = flags + dir * 1024;  // 32 flags, 32-int (128B) stride
  const int u0 = blk * 16;
  __shared__ __align__(16) u16 hstage[64 * 512];   // 64KB, XOR-swizzled rows
  __shared__ __align__(16) float xch[4][64][16];   // 16KB gate partials (kh=1)
  const int tid = threadIdx.x, lane = tid & 63;
  const int wv = tid >> 6;
  const int l15 = lane & 15, q = lane >> 4;
  const int kh = wv >> 2, bt = wv & 3;
  const int b = bt * 16 + l15;        // batch this thread's fragment covers

  // weights: 4 gates x 8 kc fragments (rows g*512+u0+l15, k = kh*256+kc*32+q*8)
  float4_ swf[4][8];
#pragma unroll
  for (int g = 0; g < 4; ++g)
#pragma unroll
    for (int kc = 0; kc < 8; ++kc)
      swf[g][kc] = *(const float4a*)(whh + (long long)(g * 512 + u0 + l15) * 512 +
                                     kh * 256 + kc * 32 + q * 8);

  float c4[4];
#pragma unroll
  for (int j = 0; j < 4; ++j) c4[j] = 0.f;

  ull pr[4], prn[4];
  if (kh == 0) {
    const int t0 = dir ? 255 : 0;
    const u16* pb = pre + (long long)(t0 * 64 + b) * 2048 + u0 + q * 4;
#pragma unroll
    for (int g = 0; g < 4; ++g) pr[g] = *(const ulla*)(pb + g * 512);
  }

  for (int tt = 0; tt < 256; ++tt) {
    const int t = dir ? (255 - tt) : tt;

    // ---- stage h_{t-1}: coalesced (per-wave 1KB contiguous per b128) ----
    {
      const u16* base;
      if (tt == 0) {
        base = zbuf + dir * 512;
      } else {
        const int tp = dir ? (t + 1) : (t - 1);
        base = o_out + (long long)tp * 65536 + dir * 512;
      }
      const int off = lane * 8;
#pragma unroll
      for (int it = 0; it < 8; ++it) {
        const int row = wv + it * 8;
        const float4_ v = *(const float4a*)(base + (long long)row * 1024 + off);
        *(float4a*)((char*)hstage + row * 1024 + ((off * 2) ^ ((row & 7) << 4))) = v;
      }
    }
    __syncthreads();

    // ---- MFMA: 4 gates, one A-read per kc (reused 4x) ----
    float4_ acc[4];
#pragma unroll
    for (int g = 0; g < 4; ++g) acc[g] = splat4(0.f);
    const char* hsb = (const char*)hstage;
#pragma unroll
    for (int kc = 0; kc < 8; ++kc) {
      const int row = b;
      const short8 A = *(const short8a*)(hsb + row * 1024 +
                        ((kh * 512 + kc * 64 + q * 16) ^ ((row & 7) << 4)));
      acc[0] = MFMA16(__builtin_bit_cast(short8, swf[0][kc]), A, acc[0]);
      acc[1] = MFMA16(__builtin_bit_cast(short8, swf[1][kc]), A, acc[1]);
      acc[2] = MFMA16(__builtin_bit_cast(short8, swf[2][kc]), A, acc[2]);
      acc[3] = MFMA16(__builtin_bit_cast(short8, swf[3][kc]), A, acc[3]);
    }

    // ---- exchange: kh=1 writes partials; kh=0 sums + activates + publishes ----
    if (kh == 1) {
#pragma unroll
      for (int g = 0; g < 4; ++g)
        *(float4a*)&xch[g][b][(q ^ (l15 & 3)) * 4] = acc[g];
    }
    __syncthreads();
    if (kh == 0) {
#pragma unroll
      for (int g = 0; g < 4; ++g)
        acc[g] += *(const float4a*)&xch[g][b][(q ^ (l15 & 3)) * 4];
      ull hv = 0;
#pragma unroll
      for (int j = 0; j < 4; ++j) {
        const float iv = acc[0][j] + b2f((u16)(pr[0] >> (16 * j)));
        const float fv = acc[1][j] + b2f((u16)(pr[1] >> (16 * j)));
        const float gg = acc[2][j] + b2f((u16)(pr[2] >> (16 * j)));
        const float ov = acc[3][j] + b2f((u16)(pr[3] >> (16 * j)));
        c4[j] = sigm(fv) * c4[j] + sigm(iv) * tanh_(gg);
        const float h = sigm(ov) * tanh_(c4[j]);
        hv |= (ull)f2b(h) << (16 * j);
      }
      __hip_atomic_store((ull*)(o_out + (long long)(t * 64 + b) * 1024 + dir * 512 + u0 + q * 4), hv,
                         __ATOMIC_RELAXED, __HIP_MEMORY_SCOPE_AGENT);
    }
    asm volatile("s_waitcnt vmcnt(0)" ::: "memory");  // h at coherence point
    __syncthreads();
    if (tid == 0)
      __hip_atomic_store(&myflags[blk * 32], tt + 1, __ATOMIC_RELAXED, __HIP_MEMORY_SCOPE_AGENT);
    if (kh == 0) {
      const int ttn = (tt < 255) ? tt + 1 : tt;
      const int tn = dir ? (255 - ttn) : ttn;
      const u16* pb = pre + (long long)(tn * 64 + b) * 2048 + u0 + q * 4;
#pragma unroll
      for (int g = 0; g < 4; ++g) prn[g] = *(const ulla*)(pb + g * 512);
    }
    if (tt != 255) {
      const int* fp = myflags + (lane & 31) * 32;
      int v = __hip_atomic_load(fp, __ATOMIC_RELAXED, __HIP_MEMORY_SCOPE_AGENT);
      while (__all(v >= tt + 1) == 0) {
        __builtin_amdgcn_s_sleep(1);
        v = __hip_atomic_load(fp, __ATOMIC_RELAXED, __HIP_MEMORY_SCOPE_AGENT);
      }
      asm volatile("" ::: "memory");
    }
    if (kh == 0) {
#pragma unroll
      for (int g = 0; g < 4; ++g) pr[g] = prn[g];
    }
#pragma unroll
    for (int g = 0; g < 4; ++g)
#pragma unroll
      for (int kc = 0; kc < 8; ++kc) asm volatile("" : "+v"(swf[g][kc]));
  }
}

// ---------------- launcher ----------------
static constexpr long long OFF_WT = 0;
static constexpr long long OFF_BIAS = 19660800;
static constexpr long long OFF_CAT = 19698944;
static constexpr long long OFF_EMB = 36476160;
static constexpr long long OFF_PRE = 44864768;
static constexpr long long OFF_O1 = 179082496;
static constexpr long long OFF_O2 = 212636928;
static constexpr long long OFF_SYNC = 246191360;
static constexpr long long SYNC_BYTES = 16384 + 131072;  // padded flags + zero slot
static constexpr long long OFF_FLAG = OFF_SYNC + SYNC_BYTES;

extern "C" void kernel_launch(void* const* d_in, const int* in_sizes, int n_in,
                              void* d_out, int out_size, void* d_ws, size_t ws_size,
                              hipStream_t stream) {
  char* ws = (char*)d_ws;
  u16* wt = (u16*)(ws + OFF_WT);
  float* biasp = (float*)(ws + OFF_BIAS);
  u16* cat = (u16*)(ws + OFF_CAT);
  u16* emb = (u16*)(ws + OFF_EMB);
  u16* pre0 = (u16*)(ws + OFF_PRE);
  u16* pre1 = pre0 + (long long)16384 * 2048;
  u16* o1 = (u16*)(ws + OFF_O1);
  u16* o2 = (u16*)(ws + OFF_O2);
  int* cnt1 = (int*)(ws + OFF_SYNC);          // 2 dirs x 32 flags x 32-int stride
  int* cnt2 = cnt1 + 2048;
  u16* zbuf = (u16*)(ws + OFF_SYNC + 16384);  // 128KB zero slot
  int* flag = (int*)(ws + OFF_FLAG);

  hipMemsetAsync(ws + OFF_SYNC, 0, SYNC_BYTES, stream);
  k_detect<<<1, 256, 0, stream>>>((const unsigned*)d_in[30], flag);

  WSegs wsg;
  const int widx[14] = {4, 5, 8, 9, 12, 13, 16, 17, 20, 21, 24, 25, 28, 30};
  const int wdst[15] = {0, 32768, 98304, 131072, 196608, 720896, 1769472, 2293760,
                        3342336, 5439488, 6488064, 8585216, 9633792, 9764864, 9816064};
  const int wn[15] = {32768, 65536, 32768, 65536, 524288, 1048576, 524288, 1048576,
                      2097152, 1048576, 2097152, 1048576, 131072, 51200, 14336};
  for (int j = 0; j < 14; ++j) { wsg.src[j] = d_in[widx[j]]; wsg.dst[j] = wdst[j]; wsg.n[j] = wn[j]; }
  wsg.src[14] = nullptr; wsg.dst[14] = wdst[14]; wsg.n[14] = wn[14];
  k_convw<<<1200, 256, 0, stream>>>(wsg, wt, flag);

  BSegs bsg;
  const int ba[8] = {6, 10, 14, 18, 22, 26, 29, 31};
  const int bb[8] = {7, 11, 15, 19, 23, 27, -1, -1};
  const int bdst[8] = {0, 512, 1024, 3072, 5120, 7168, 9216, 9472};
  const int bn_[8] = {512, 512, 2048, 2048, 2048, 2048, 256, 50};
  const int bnp[8] = {512, 512, 2048, 2048, 2048, 2048, 256, 64};
  for (int j = 0; j < 8; ++j) {
    bsg.a[j] = d_in[ba[j]];
    bsg.b[j] = (bb[j] >= 0) ? d_in[bb[j]] : nullptr;
    bsg.dst[j] = bdst[j]; bsg.n[j] = bn_[j]; bsg.np[j] = bnp[j];
  }
  k_convb<<<40, 256, 0, stream>>>(bsg, biasp, flag);

  k_wordgather<<<2048, 256, 0, stream>>>((const int*)d_in[0], d_in[2], cat, flag);
  k_char<<<dim3(256, 2), 256, 0, stream>>>((const int*)d_in[1], d_in[3],
                                           wt + 0, wt + 32768, wt + 98304, wt + 131072,
                                           biasp + 0, biasp + 512, cat, flag);
  k_gemm2<1, 0><<<dim3(128, 2), 256, 0, stream>>>(cat, wt + 9633792, biasp + 9216, emb, 256, 512, 256, flag);
  k_gemm2<0, 0><<<dim3(128, 16), 256, 0, stream>>>(emb, wt + 196608, biasp + 1024, pre0, 2048, 256, 2048, flag);
  k_gemm2<0, 0><<<dim3(128, 16), 256, 0, stream>>>(emb, wt + 1769472, biasp + 3072, pre1, 2048, 256, 2048, flag);
  k_scan<<<dim3(32, 2), 512, 0, stream>>>(pre0, pre1, wt + 720896, wt + 2293760, o1, zbuf, cnt1);
  k_gemm2<0, 0><<<dim3(128, 16), 256, 0, stream>>>(o1, wt + 3342336, biasp + 5120, pre0, 2048, 1024, 2048, flag);
  k_gemm2<0, 0><<<dim3(128, 16), 256, 0, stream>>>(o1, wt + 6488064, biasp + 7168, pre1, 2048, 1024, 2048, flag);
  k_scan<<<dim3(32, 2), 512, 0, stream>>>(pre0, pre1, wt + 5439488, wt + 8585216, o2, zbuf, cnt2);
  k_gemm<64, 64, 2, 1><<<dim3(256, 1), 256, 0, stream>>>(o2, wt + 9764864, biasp + 9472, d_out, 50, 1024, 50, flag);
}